// Round 3
// baseline (713.260 us; speedup 1.0000x reference)
//
#include <hip/hip_runtime.h>
#include <hip/hip_bf16.h>
#include <math.h>

#define FF 256      // feature dim (K of GEMM)
#define UU 256      // units (N of GEMM)
#define DD 128      // mean/var split
#define BM 64       // GEMM row tile
#define BK 32       // GEMM k tile
#define AS_LD 36    // padded LDS leading dim for A tile (multiple of 4, breaks power-of-2 stride)

// ---------------------------------------------------------------------------
// Kernel 1: h = A@B fused with elu/relu, kl partial, att, xmv = [m*att | v*att^2]
// ---------------------------------------------------------------------------
__global__ __launch_bounds__(256, 3)
void gemm_fused_kernel(const float* __restrict__ A,      // [n, 256]
                       const float* __restrict__ B,      // [256, 256]
                       float* __restrict__ xmv,          // [n, 256] ws
                       float* __restrict__ klpart,       // [gridDim.x] ws
                       int n) {
    __shared__ float As[BM * AS_LD];   // 9.2 KB
    __shared__ float Bs[BK * UU];      // 32 KB
    __shared__ float kls[4];

    const int t  = threadIdx.x;
    const int tx = t & 15;   // col group 0..15
    const int ty = t >> 4;   // row group 0..15
    const int r0 = blockIdx.x * BM;

    float acc[4][4][4];      // [row i][col group j][lane-in-group l]; col = tx*4 + j*64 + l
    #pragma unroll
    for (int i = 0; i < 4; ++i)
        #pragma unroll
        for (int j = 0; j < 4; ++j)
            #pragma unroll
            for (int l = 0; l < 4; ++l) acc[i][j][l] = 0.f;

    for (int kt = 0; kt < FF; kt += BK) {
        // stage A tile: 64 rows x 32 k = 512 float4, 2 per thread
        #pragma unroll
        for (int s = 0; s < 2; ++s) {
            int idx = t + 256 * s;           // 0..511
            int r   = idx >> 3;              // 0..63
            int km  = (idx & 7) << 2;        // 0..28
            int gr  = r0 + r; if (gr > n - 1) gr = n - 1;   // clamp for tail block
            float4 v = *(const float4*)(A + (size_t)gr * FF + kt + km);
            *(float4*)(As + r * AS_LD + km) = v;
        }
        // stage B tile: 32 k x 256 = 2048 float4, 8 per thread
        #pragma unroll
        for (int s = 0; s < 8; ++s) {
            int idx = t + 256 * s;           // 0..2047
            int kk  = idx >> 6;              // 0..31
            int cc  = (idx & 63) << 2;       // 0..252
            float4 v = *(const float4*)(B + (size_t)(kt + kk) * UU + cc);
            *(float4*)(Bs + kk * UU + cc) = v;
        }
        __syncthreads();

        #pragma unroll 2
        for (int k4 = 0; k4 < BK; k4 += 4) {
            float4 a[4];
            #pragma unroll
            for (int i = 0; i < 4; ++i)
                a[i] = *(const float4*)(As + (ty * 4 + i) * AS_LD + k4);
            #pragma unroll
            for (int kk = 0; kk < 4; ++kk) {
                float4 b[4];
                #pragma unroll
                for (int j = 0; j < 4; ++j)
                    b[j] = *(const float4*)(Bs + (k4 + kk) * UU + tx * 4 + j * 64);
                #pragma unroll
                for (int i = 0; i < 4; ++i) {
                    const float ai = ((const float*)&a[i])[kk];
                    #pragma unroll
                    for (int j = 0; j < 4; ++j) {
                        acc[i][j][0] = fmaf(ai, b[j].x, acc[i][j][0]);
                        acc[i][j][1] = fmaf(ai, b[j].y, acc[i][j][1]);
                        acc[i][j][2] = fmaf(ai, b[j].z, acc[i][j][2]);
                        acc[i][j][3] = fmaf(ai, b[j].w, acc[i][j][3]);
                    }
                }
            }
        }
        __syncthreads();
    }

    // epilogue: cols tx*4+j*64 for j=0,1 are the mean half; j+2 is the paired var half (+128)
    float klsum = 0.f;
    #pragma unroll
    for (int i = 0; i < 4; ++i) {
        const int gr = r0 + ty * 4 + i;
        if (gr < n) {
            #pragma unroll
            for (int j = 0; j < 2; ++j) {
                float4 xm4, xv4;
                #pragma unroll
                for (int l = 0; l < 4; ++l) {
                    float h1 = acc[i][j][l];       // mean pre-act
                    float h2 = acc[i][j + 2][l];   // var pre-act (col +128)
                    float m = h1 > 0.f ? h1 : expm1f(h1);   // elu
                    float v = h2 > 0.f ? h2 : 0.f;          // relu
                    klsum += m * m + v - logf(1e-8f + v) - 1.f;
                    float att = expf(-v);                   // GAMMA = 1
                    ((float*)&xm4)[l] = m * att;
                    ((float*)&xv4)[l] = v * att * att;
                }
                const int c = tx * 4 + j * 64;
                *(float4*)(xmv + (size_t)gr * UU + c)      = xm4;
                *(float4*)(xmv + (size_t)gr * UU + c + DD) = xv4;
            }
        }
    }

    // kl block reduce
    #pragma unroll
    for (int off = 32; off > 0; off >>= 1)
        klsum += __shfl_down(klsum, off, 64);
    if ((t & 63) == 0) kls[t >> 6] = klsum;
    __syncthreads();
    if (t == 0) klpart[blockIdx.x] = kls[0] + kls[1] + kls[2] + kls[3];
}

// ---------------------------------------------------------------------------
// Kernel 2a: rowptr[r] = lower_bound(row, r) for r in [0, n]; row[] sorted.
// One thread per row, fully parallel; row array (6.4 MB) is L2-resident.
// ---------------------------------------------------------------------------
__global__ __launch_bounds__(256)
void rowptr_kernel(const int* __restrict__ rowi, int* __restrict__ rowptr,
                   int n, int e) {
    const int r = blockIdx.x * 256 + threadIdx.x;
    if (r > n) return;
    int lo = 0, hi = e;
    while (lo < hi) { int mid = (lo + hi) >> 1; if (rowi[mid] < r) lo = mid + 1; else hi = mid; }
    rowptr[r] = lo;
}

// ---------------------------------------------------------------------------
// Kernel 2b: SpMM, one block per output row; no atomics, every row written
// (empty rows write 0 over poisoned d_out).
// ---------------------------------------------------------------------------
__global__ __launch_bounds__(256, 8)
void spmm_kernel(const int* __restrict__ rowptr,
                 const int* __restrict__ coli,
                 const float* __restrict__ w1,
                 const float* __restrict__ w2,
                 const float* __restrict__ xmv,
                 float* __restrict__ out) {
    const int r = blockIdx.x;
    const int d = threadIdx.x;

    const int lb = rowptr[r];
    const int ub = rowptr[r + 1];

    const float* __restrict__ wsrc = (d < DD) ? w1 : w2;
    float acc = 0.f;
    for (int e = lb; e < ub; ++e) {
        const int c   = coli[e];                      // uniform
        const float w = wsrc[e];                      // uniform per half
        acc = fmaf(w, xmv[(size_t)c * UU + d], acc);  // coalesced 1KB row gather
    }
    out[(size_t)r * UU + d] = acc;
}

// ---------------------------------------------------------------------------
// Kernel 3: reduce kl partials, write scalar (no atomic onto poisoned d_out)
// ---------------------------------------------------------------------------
__global__ __launch_bounds__(256)
void klreduce_kernel(const float* __restrict__ klpart, int nparts,
                     float* __restrict__ dst) {
    __shared__ float tmp[4];
    const int t = threadIdx.x;
    float s = 0.f;
    for (int i = t; i < nparts; i += 256) s += klpart[i];
    #pragma unroll
    for (int off = 32; off > 0; off >>= 1)
        s += __shfl_down(s, off, 64);
    if ((t & 63) == 0) tmp[t >> 6] = s;
    __syncthreads();
    if (t == 0) dst[0] = (0.5f / (float)DD) * (tmp[0] + tmp[1] + tmp[2] + tmp[3]);
}

// ---------------------------------------------------------------------------
extern "C" void kernel_launch(void* const* d_in, const int* in_sizes, int n_in,
                              void* d_out, int out_size, void* d_ws, size_t ws_size,
                              hipStream_t stream) {
    const float* features = (const float*)d_in[0];
    const float* kernelW  = (const float*)d_in[1];
    const int*   row      = (const int*)d_in[2];
    const int*   col      = (const int*)d_in[3];
    const float* a1       = (const float*)d_in[4];
    const float* a2       = (const float*)d_in[5];
    float*       out      = (float*)d_out;

    const int n = in_sizes[0] / FF;     // 100000
    const int e = in_sizes[2];          // 1600000

    float* xmv    = (float*)d_ws;                   // n*256 f32 = 102.4 MB
    float* klpart = xmv + (size_t)n * UU;           // nblocks f32
    int*   rowptr = (int*)(klpart + 4096);          // n+1 ints

    const int nblocks = (n + BM - 1) / BM;          // 1563

    gemm_fused_kernel<<<nblocks, 256, 0, stream>>>(features, kernelW, xmv, klpart, n);
    rowptr_kernel<<<(n + 256) / 256, 256, 0, stream>>>(row, rowptr, n, e);
    spmm_kernel<<<n, 256, 0, stream>>>(rowptr, col, a1, a2, xmv, out);
    klreduce_kernel<<<1, 256, 0, stream>>>(klpart, nblocks, out + (size_t)n * UU);
}

// Round 4
// 664.791 us; speedup vs baseline: 1.0729x; 1.0729x over previous
//
#include <hip/hip_runtime.h>
#include <hip/hip_bf16.h>
#include <math.h>

#define FF 256      // feature dim (K of GEMM)
#define UU 256      // units (N of GEMM)
#define DD 128      // mean/var split
#define BM 128      // GEMM row tile (two 64-row groups)
#define BK 32       // GEMM k tile
#define AS_LD 36    // padded LDS leading dim; group stride 64*36 % 32 == 0 but within-group
                    // row stride 4*36 gives 2-way (free) bank aliasing on a-reads

// ---------------------------------------------------------------------------
// Kernel 1: h = A@B fused with elu/relu, kl partial, att, xmv = [m*att | v*att^2]
// Per-thread microtile: 8 rows (2 groups of 4) x 16 cols. VALU-bound by design:
// per k4-step 24 ds_read_b128 vs 512 v_fmac per wave.
// ---------------------------------------------------------------------------
__global__ __launch_bounds__(256, 2)
void gemm_fused_kernel(const float* __restrict__ A,      // [n, 256]
                       const float* __restrict__ B,      // [256, 256]
                       float* __restrict__ xmv,          // [n, 256] ws
                       float* __restrict__ klpart,       // [gridDim.x] ws
                       int n) {
    __shared__ float As[BM * AS_LD];   // 18.4 KB
    __shared__ float Bs[BK * UU];      // 32 KB
    __shared__ float kls[4];

    const int t  = threadIdx.x;
    const int tx = t & 15;   // col group 0..15
    const int ty = t >> 4;   // row group 0..15
    const int r0 = blockIdx.x * BM;

    float4 acc[2][4][4];     // [group g][row i][col group j]; col = tx*4 + j*64 (+l)
    #pragma unroll
    for (int g = 0; g < 2; ++g)
        #pragma unroll
        for (int i = 0; i < 4; ++i)
            #pragma unroll
            for (int j = 0; j < 4; ++j)
                acc[g][i][j] = make_float4(0.f, 0.f, 0.f, 0.f);

    for (int kt = 0; kt < FF; kt += BK) {
        // stage A tile: 128 rows x 32 k = 1024 float4, 4 per thread
        #pragma unroll
        for (int s = 0; s < 4; ++s) {
            int idx = t + 256 * s;           // 0..1023
            int r   = idx >> 3;              // 0..127
            int km  = (idx & 7) << 2;        // 0..28
            int gr  = r0 + r; if (gr > n - 1) gr = n - 1;   // clamp for tail block
            float4 v = *(const float4*)(A + (size_t)gr * FF + kt + km);
            *(float4*)(As + r * AS_LD + km) = v;
        }
        // stage B tile: 32 k x 256 = 2048 float4, 8 per thread
        #pragma unroll
        for (int s = 0; s < 8; ++s) {
            int idx = t + 256 * s;           // 0..2047
            int kk  = idx >> 6;              // 0..31
            int cc  = (idx & 63) << 2;       // 0..252
            float4 v = *(const float4*)(B + (size_t)(kt + kk) * UU + cc);
            *(float4*)(Bs + kk * UU + cc) = v;
        }
        __syncthreads();

        #pragma unroll 2
        for (int k4 = 0; k4 < BK; k4 += 4) {
            float4 a[2][4];
            #pragma unroll
            for (int g = 0; g < 2; ++g)
                #pragma unroll
                for (int i = 0; i < 4; ++i)
                    a[g][i] = *(const float4*)(As + (g * 64 + ty * 4 + i) * AS_LD + k4);
            #pragma unroll
            for (int kk = 0; kk < 4; ++kk) {
                float4 b[4];
                #pragma unroll
                for (int j = 0; j < 4; ++j)
                    b[j] = *(const float4*)(Bs + (k4 + kk) * UU + tx * 4 + j * 64);
                #pragma unroll
                for (int g = 0; g < 2; ++g)
                    #pragma unroll
                    for (int i = 0; i < 4; ++i) {
                        const float ai = ((const float*)&a[g][i])[kk];
                        #pragma unroll
                        for (int j = 0; j < 4; ++j) {
                            acc[g][i][j].x = fmaf(ai, b[j].x, acc[g][i][j].x);
                            acc[g][i][j].y = fmaf(ai, b[j].y, acc[g][i][j].y);
                            acc[g][i][j].z = fmaf(ai, b[j].z, acc[g][i][j].z);
                            acc[g][i][j].w = fmaf(ai, b[j].w, acc[g][i][j].w);
                        }
                    }
            }
        }
        __syncthreads();
    }

    // epilogue: cols tx*4+j*64 for j=0,1 are the mean half; j+2 is the paired var half (+128)
    float klsum = 0.f;
    #pragma unroll
    for (int g = 0; g < 2; ++g)
        #pragma unroll
        for (int i = 0; i < 4; ++i) {
            const int gr = r0 + g * 64 + ty * 4 + i;
            if (gr < n) {
                #pragma unroll
                for (int j = 0; j < 2; ++j) {
                    float4 xm4, xv4;
                    #pragma unroll
                    for (int l = 0; l < 4; ++l) {
                        float h1 = ((const float*)&acc[g][i][j])[l];       // mean pre-act
                        float h2 = ((const float*)&acc[g][i][j + 2])[l];   // var pre-act (+128)
                        float m = h1 > 0.f ? h1 : expm1f(h1);   // elu
                        float v = h2 > 0.f ? h2 : 0.f;          // relu
                        klsum += m * m + v - logf(1e-8f + v) - 1.f;
                        float att = expf(-v);                   // GAMMA = 1
                        ((float*)&xm4)[l] = m * att;
                        ((float*)&xv4)[l] = v * att * att;
                    }
                    const int c = tx * 4 + j * 64;
                    *(float4*)(xmv + (size_t)gr * UU + c)      = xm4;
                    *(float4*)(xmv + (size_t)gr * UU + c + DD) = xv4;
                }
            }
        }

    // kl block reduce
    #pragma unroll
    for (int off = 32; off > 0; off >>= 1)
        klsum += __shfl_down(klsum, off, 64);
    if ((t & 63) == 0) kls[t >> 6] = klsum;
    __syncthreads();
    if (t == 0) klpart[blockIdx.x] = kls[0] + kls[1] + kls[2] + kls[3];
}

// ---------------------------------------------------------------------------
// Kernel 2a: rowptr[r] = lower_bound(row, r) for r in [0, n]; row[] sorted.
// ---------------------------------------------------------------------------
__global__ __launch_bounds__(256)
void rowptr_kernel(const int* __restrict__ rowi, int* __restrict__ rowptr,
                   int n, int e) {
    const int r = blockIdx.x * 256 + threadIdx.x;
    if (r > n) return;
    int lo = 0, hi = e;
    while (lo < hi) { int mid = (lo + hi) >> 1; if (rowi[mid] < r) lo = mid + 1; else hi = mid; }
    rowptr[r] = lo;
}

// ---------------------------------------------------------------------------
// Kernel 2b: SpMM. One WAVE per row, float4 per lane (1KB/row), 4-edge ILP
// with independent accumulators -> 4 outstanding 1KB gathers per wave.
// Lane<32 handles dims 0..127 (mean, w1); lane>=32 dims 128..255 (var, w2).
// ---------------------------------------------------------------------------
__global__ __launch_bounds__(256)
void spmm_kernel(const int* __restrict__ rowptr,
                 const int* __restrict__ coli,
                 const float* __restrict__ w1,
                 const float* __restrict__ w2,
                 const float* __restrict__ xmv,
                 float* __restrict__ out,
                 int n) {
    const int lane = threadIdx.x & 63;
    const int wv   = threadIdx.x >> 6;          // wave 0..3 within block
    const int r    = blockIdx.x * 4 + wv;
    if (r >= n) return;

    const float4* __restrict__ x4 = (const float4*)xmv;
    const int lb = rowptr[r];
    const int ub = rowptr[r + 1];
    const float* __restrict__ wsrc = (lane < 32) ? w1 : w2;

    float4 a0 = make_float4(0.f,0.f,0.f,0.f), a1 = a0, a2 = a0, a3 = a0;
    int e = lb;
    for (; e + 4 <= ub; e += 4) {
        const int c0 = coli[e], c1 = coli[e+1], c2 = coli[e+2], c3 = coli[e+3];
        const float w0 = wsrc[e], w1v = wsrc[e+1], w2v = wsrc[e+2], w3v = wsrc[e+3];
        const float4 x0 = x4[(size_t)c0 * 64 + lane];
        const float4 x1 = x4[(size_t)c1 * 64 + lane];
        const float4 x2 = x4[(size_t)c2 * 64 + lane];
        const float4 x3 = x4[(size_t)c3 * 64 + lane];
        a0.x = fmaf(w0, x0.x, a0.x); a0.y = fmaf(w0, x0.y, a0.y);
        a0.z = fmaf(w0, x0.z, a0.z); a0.w = fmaf(w0, x0.w, a0.w);
        a1.x = fmaf(w1v, x1.x, a1.x); a1.y = fmaf(w1v, x1.y, a1.y);
        a1.z = fmaf(w1v, x1.z, a1.z); a1.w = fmaf(w1v, x1.w, a1.w);
        a2.x = fmaf(w2v, x2.x, a2.x); a2.y = fmaf(w2v, x2.y, a2.y);
        a2.z = fmaf(w2v, x2.z, a2.z); a2.w = fmaf(w2v, x2.w, a2.w);
        a3.x = fmaf(w3v, x3.x, a3.x); a3.y = fmaf(w3v, x3.y, a3.y);
        a3.z = fmaf(w3v, x3.z, a3.z); a3.w = fmaf(w3v, x3.w, a3.w);
    }
    for (; e < ub; ++e) {
        const int c = coli[e];
        const float w = wsrc[e];
        const float4 x = x4[(size_t)c * 64 + lane];
        a0.x = fmaf(w, x.x, a0.x); a0.y = fmaf(w, x.y, a0.y);
        a0.z = fmaf(w, x.z, a0.z); a0.w = fmaf(w, x.w, a0.w);
    }
    float4 res;
    res.x = (a0.x + a1.x) + (a2.x + a3.x);
    res.y = (a0.y + a1.y) + (a2.y + a3.y);
    res.z = (a0.z + a1.z) + (a2.z + a3.z);
    res.w = (a0.w + a1.w) + (a2.w + a3.w);
    ((float4*)out)[(size_t)r * 64 + lane] = res;
}

// ---------------------------------------------------------------------------
// Kernel 3: reduce kl partials, write scalar (no atomic onto poisoned d_out)
// ---------------------------------------------------------------------------
__global__ __launch_bounds__(256)
void klreduce_kernel(const float* __restrict__ klpart, int nparts,
                     float* __restrict__ dst) {
    __shared__ float tmp[4];
    const int t = threadIdx.x;
    float s = 0.f;
    for (int i = t; i < nparts; i += 256) s += klpart[i];
    #pragma unroll
    for (int off = 32; off > 0; off >>= 1)
        s += __shfl_down(s, off, 64);
    if ((t & 63) == 0) tmp[t >> 6] = s;
    __syncthreads();
    if (t == 0) dst[0] = (0.5f / (float)DD) * (tmp[0] + tmp[1] + tmp[2] + tmp[3]);
}

// ---------------------------------------------------------------------------
extern "C" void kernel_launch(void* const* d_in, const int* in_sizes, int n_in,
                              void* d_out, int out_size, void* d_ws, size_t ws_size,
                              hipStream_t stream) {
    const float* features = (const float*)d_in[0];
    const float* kernelW  = (const float*)d_in[1];
    const int*   row      = (const int*)d_in[2];
    const int*   col      = (const int*)d_in[3];
    const float* a1       = (const float*)d_in[4];
    const float* a2       = (const float*)d_in[5];
    float*       out      = (float*)d_out;

    const int n = in_sizes[0] / FF;     // 100000
    const int e = in_sizes[2];          // 1600000

    float* xmv    = (float*)d_ws;                   // n*256 f32 = 102.4 MB
    float* klpart = xmv + (size_t)n * UU;           // nblocks f32
    int*   rowptr = (int*)(klpart + 4096);          // n+1 ints

    const int nblocks = (n + BM - 1) / BM;          // 782

    gemm_fused_kernel<<<nblocks, 256, 0, stream>>>(features, kernelW, xmv, klpart, n);
    rowptr_kernel<<<(n + 256) / 256, 256, 0, stream>>>(row, rowptr, n, e);
    spmm_kernel<<<(n + 3) / 4, 256, 0, stream>>>(rowptr, col, a1, a2, xmv, out, n);
    klreduce_kernel<<<1, 256, 0, stream>>>(klpart, nblocks, out + (size_t)n * UU);
}

// Round 6
// 392.010 us; speedup vs baseline: 1.8195x; 1.6959x over previous
//
#include <hip/hip_runtime.h>
#include <hip/hip_bf16.h>
#include <hip/hip_fp16.h>
#include <math.h>

#define FF 256      // feature dim (K)
#define UU 256      // units (N)
#define DD 128      // mean/var split
#define BMG 64      // gemm row tile
#define BKG 32      // gemm k tile
#define ALD 40      // LDS row stride in bf16 elems (32 + 8 pad -> 80B, 16B-aligned, 2-way banks)

typedef short short8 __attribute__((ext_vector_type(8)));
typedef float f32x4  __attribute__((ext_vector_type(4)));

// round-to-nearest-even fp32 -> bf16 bits (finite inputs)
__device__ __forceinline__ unsigned short f2bf(float x) {
    unsigned int u = __float_as_uint(x);
    return (unsigned short)((u + 0x7fffu + ((u >> 16) & 1u)) >> 16);
}
__device__ __forceinline__ float bf2f(unsigned short b) {
    return __uint_as_float(((unsigned int)b) << 16);
}

// ---------------------------------------------------------------------------
// Kernel 0: split B into bf16 hi/lo, TRANSPOSED: Bt[n][k]  (LDS-transposed,
// coalesced both sides; 256KB total, ~2us)
// ---------------------------------------------------------------------------
__global__ __launch_bounds__(256)
void prep_b_kernel(const float* __restrict__ B,
                   unsigned short* __restrict__ Bth,
                   unsigned short* __restrict__ Btl) {
    __shared__ float tile[64][65];
    const int t  = threadIdx.x;
    const int k0 = (blockIdx.x & 3) * 64;
    const int n0 = (blockIdx.x >> 2) * 64;
    #pragma unroll
    for (int i = 0; i < 16; ++i) {
        int idx = t + 256 * i;
        int kk = idx >> 6, nn = idx & 63;
        tile[kk][nn] = B[(size_t)(k0 + kk) * UU + n0 + nn];
    }
    __syncthreads();
    #pragma unroll
    for (int i = 0; i < 16; ++i) {
        int idx = t + 256 * i;
        int nn = idx >> 6, kk = idx & 63;
        float b = tile[kk][nn];
        unsigned short hb = f2bf(b);
        unsigned short lb = f2bf(b - bf2f(hb));
        Bth[(size_t)(n0 + nn) * FF + k0 + kk] = hb;
        Btl[(size_t)(n0 + nn) * FF + k0 + kk] = lb;
    }
}

// ---------------------------------------------------------------------------
// Kernel 1: bf16x3 MFMA GEMM (h = A@B) fused epilogue -> xmv fp16, kl partials.
// Block: 256 thr (4 waves), BM=64 rows x all 256 cols.
// Wave w owns n-tiles {2w, 2w+1, 2w+8, 2w+9} so mean col c and var col c+128
// live in the same lane (j and j+2 pairing).
// ---------------------------------------------------------------------------
__global__ __launch_bounds__(256, 2)
void gemm_mfma_kernel(const float* __restrict__ A,
                      const unsigned short* __restrict__ Bth,
                      const unsigned short* __restrict__ Btl,
                      __half* __restrict__ xmv,
                      float* __restrict__ klpart,
                      int n) {
    __shared__ unsigned short Ah[BMG * ALD], Al[BMG * ALD];   // 5120 B each
    __shared__ unsigned short Bh[UU * ALD],  Bl[UU * ALD];    // 20480 B each
    __shared__ float kls[4];

    const int t    = threadIdx.x;
    const int lane = t & 63;
    const int w    = t >> 6;
    const int l15  = lane & 15;
    const int lk   = (lane >> 4) * 8;      // k-offset within 32-k tile
    const int r0   = blockIdx.x * BMG;

    f32x4 acc[4][4];   // [m-tile][j: 0,1 = mean tiles, 2,3 = var tiles]
    #pragma unroll
    for (int m = 0; m < 4; ++m)
        #pragma unroll
        for (int j = 0; j < 4; ++j)
            acc[m][j] = (f32x4){0.f, 0.f, 0.f, 0.f};

    // A staging map: thread -> (row t>>2, k-seg (t&3)*8)
    const int arow  = t >> 2;
    const int akseg = (t & 3) * 8;
    int garow = r0 + arow; if (garow >= n) garow = n - 1;   // clamp tail
    const float* aptr = A + (size_t)garow * FF + akseg;

    for (int kt = 0; kt < FF; kt += BKG) {
        // ---- stage A: load 8 f32, split to bf16 hi/lo, ds_write_b128 ----
        float4 a0 = *(const float4*)(aptr + kt);
        float4 a1 = *(const float4*)(aptr + kt + 4);
        float av[8] = {a0.x, a0.y, a0.z, a0.w, a1.x, a1.y, a1.z, a1.w};
        short8 hv, lv;
        #pragma unroll
        for (int i = 0; i < 8; ++i) {
            unsigned short hb = f2bf(av[i]);
            unsigned short lb = f2bf(av[i] - bf2f(hb));
            hv[i] = (short)hb; lv[i] = (short)lb;
        }
        *(short8*)(Ah + arow * ALD + akseg) = hv;
        *(short8*)(Al + arow * ALD + akseg) = lv;
        // ---- stage B tiles (pre-split bf16, transposed [n][k]) ----
        #pragma unroll
        for (int p = 0; p < 4; ++p) {
            int slot = t + 256 * p;            // 0..1023
            int nr = slot >> 2, ks = (slot & 3) * 8;
            *(short8*)(Bh + nr * ALD + ks) = *(const short8*)(Bth + (size_t)nr * FF + kt + ks);
            *(short8*)(Bl + nr * ALD + ks) = *(const short8*)(Btl + (size_t)nr * FF + kt + ks);
        }
        __syncthreads();

        // ---- fragments: A row = l15, k = lk+e ; B col = l15, k = lk+e ----
        short8 fah[4], fal[4], fbh[4], fbl[4];
        #pragma unroll
        for (int m = 0; m < 4; ++m) {
            int row = 16 * m + l15;
            fah[m] = *(const short8*)(Ah + row * ALD + lk);
            fal[m] = *(const short8*)(Al + row * ALD + lk);
        }
        #pragma unroll
        for (int j = 0; j < 4; ++j) {
            int nn = (j < 2) ? (32 * w + 16 * j + l15)
                             : (DD + 32 * w + 16 * (j - 2) + l15);
            fbh[j] = *(const short8*)(Bh + nn * ALD + lk);
            fbl[j] = *(const short8*)(Bl + nn * ALD + lk);
        }
        #pragma unroll
        for (int m = 0; m < 4; ++m)
            #pragma unroll
            for (int j = 0; j < 4; ++j) {
                acc[m][j] = __builtin_amdgcn_mfma_f32_16x16x32_bf16(fah[m], fbh[j], acc[m][j], 0, 0, 0);
                acc[m][j] = __builtin_amdgcn_mfma_f32_16x16x32_bf16(fal[m], fbh[j], acc[m][j], 0, 0, 0);
                acc[m][j] = __builtin_amdgcn_mfma_f32_16x16x32_bf16(fah[m], fbl[j], acc[m][j], 0, 0, 0);
            }
        __syncthreads();
    }

    // ---- fused epilogue: D row = (lane>>4)*4 + reg, col = l15 (m89-verified)
    float klsum = 0.f;
    const int rbase = (lane >> 4) * 4;
    #pragma unroll
    for (int m = 0; m < 4; ++m)
        #pragma unroll
        for (int reg = 0; reg < 4; ++reg) {
            const int gr = r0 + 16 * m + rbase + reg;
            if (gr < n) {
                #pragma unroll
                for (int j = 0; j < 2; ++j) {
                    float h1 = acc[m][j][reg];       // mean pre-act
                    float h2 = acc[m][j + 2][reg];   // var pre-act (col +128)
                    float mm = h1 > 0.f ? h1 : expm1f(h1);   // elu
                    float vv = h2 > 0.f ? h2 : 0.f;          // relu
                    klsum += mm * mm + vv - logf(1e-8f + vv) - 1.f;
                    float att = expf(-vv);                   // GAMMA = 1
                    const int cm = 32 * w + 16 * j + l15;
                    xmv[(size_t)gr * UU + cm]      = __float2half(mm * att);
                    xmv[(size_t)gr * UU + cm + DD] = __float2half(vv * att * att);
                }
            }
        }

    #pragma unroll
    for (int off = 32; off > 0; off >>= 1)
        klsum += __shfl_down(klsum, off, 64);
    if (lane == 0) kls[w] = klsum;
    __syncthreads();
    if (t == 0) klpart[blockIdx.x] = kls[0] + kls[1] + kls[2] + kls[3];
}

// ---------------------------------------------------------------------------
// Kernel 2a: rowptr[r] = lower_bound(row, r), r in [0, n]
// ---------------------------------------------------------------------------
__global__ __launch_bounds__(256)
void rowptr_kernel(const int* __restrict__ rowi, int* __restrict__ rowptr,
                   int n, int e) {
    const int r = blockIdx.x * 256 + threadIdx.x;
    if (r > n) return;
    int lo = 0, hi = e;
    while (lo < hi) { int mid = (lo + hi) >> 1; if (rowi[mid] < r) lo = mid + 1; else hi = mid; }
    rowptr[r] = lo;
}

// ---------------------------------------------------------------------------
// Kernel 2b: SpMM over fp16 xmv. One wave per row, 8B/lane (4 halfs), 4-edge
// ILP; nontemporal for streamed edge data and out (keep L3 for xmv gather).
// ---------------------------------------------------------------------------
__device__ __forceinline__ void fma4h(float4& a, float w, uint2 v) {
    __half2 p = *(__half2*)&v.x, q = *(__half2*)&v.y;
    float2 pf = __half22float2(p), qf = __half22float2(q);
    a.x = fmaf(w, pf.x, a.x); a.y = fmaf(w, pf.y, a.y);
    a.z = fmaf(w, qf.x, a.z); a.w = fmaf(w, qf.y, a.w);
}

__global__ __launch_bounds__(256)
void spmm_kernel(const int* __restrict__ rowptr,
                 const int* __restrict__ coli,
                 const float* __restrict__ w1,
                 const float* __restrict__ w2,
                 const __half* __restrict__ xmv,
                 float* __restrict__ out,
                 int n) {
    const int lane = threadIdx.x & 63;
    const int wv   = threadIdx.x >> 6;
    const int r    = blockIdx.x * 4 + wv;
    if (r >= n) return;

    const uint2* __restrict__ x2 = (const uint2*)xmv;   // 4 halfs / lane
    const int lb = rowptr[r];
    const int ub = rowptr[r + 1];
    const float* __restrict__ wsrc = (lane < 32) ? w1 : w2;

    float4 a0 = make_float4(0.f,0.f,0.f,0.f), a1 = a0, a2 = a0, a3 = a0;
    int e = lb;
    for (; e + 4 <= ub; e += 4) {
        const int c0 = __builtin_nontemporal_load(coli + e);
        const int c1 = __builtin_nontemporal_load(coli + e + 1);
        const int c2 = __builtin_nontemporal_load(coli + e + 2);
        const int c3 = __builtin_nontemporal_load(coli + e + 3);
        const float w0 = __builtin_nontemporal_load(wsrc + e);
        const float w1v = __builtin_nontemporal_load(wsrc + e + 1);
        const float w2v = __builtin_nontemporal_load(wsrc + e + 2);
        const float w3v = __builtin_nontemporal_load(wsrc + e + 3);
        const uint2 v0 = x2[(size_t)c0 * 64 + lane];
        const uint2 v1 = x2[(size_t)c1 * 64 + lane];
        const uint2 v2 = x2[(size_t)c2 * 64 + lane];
        const uint2 v3 = x2[(size_t)c3 * 64 + lane];
        fma4h(a0, w0, v0); fma4h(a1, w1v, v1);
        fma4h(a2, w2v, v2); fma4h(a3, w3v, v3);
    }
    for (; e < ub; ++e) {
        const int c = coli[e];
        const float w = wsrc[e];
        fma4h(a0, w, x2[(size_t)c * 64 + lane]);
    }
    f32x4 res;
    res[0] = (a0.x + a1.x) + (a2.x + a3.x);
    res[1] = (a0.y + a1.y) + (a2.y + a3.y);
    res[2] = (a0.z + a1.z) + (a2.z + a3.z);
    res[3] = (a0.w + a1.w) + (a2.w + a3.w);
    __builtin_nontemporal_store(res, (f32x4*)out + (size_t)r * 64 + lane);
}

// ---------------------------------------------------------------------------
// Kernel 3: reduce kl partials
// ---------------------------------------------------------------------------
__global__ __launch_bounds__(256)
void klreduce_kernel(const float* __restrict__ klpart, int nparts,
                     float* __restrict__ dst) {
    __shared__ float tmp[4];
    const int t = threadIdx.x;
    float s = 0.f;
    for (int i = t; i < nparts; i += 256) s += klpart[i];
    #pragma unroll
    for (int off = 32; off > 0; off >>= 1)
        s += __shfl_down(s, off, 64);
    if ((t & 63) == 0) tmp[t >> 6] = s;
    __syncthreads();
    if (t == 0) dst[0] = (0.5f / (float)DD) * (tmp[0] + tmp[1] + tmp[2] + tmp[3]);
}

// ---------------------------------------------------------------------------
extern "C" void kernel_launch(void* const* d_in, const int* in_sizes, int n_in,
                              void* d_out, int out_size, void* d_ws, size_t ws_size,
                              hipStream_t stream) {
    const float* features = (const float*)d_in[0];
    const float* kernelW  = (const float*)d_in[1];
    const int*   row      = (const int*)d_in[2];
    const int*   col      = (const int*)d_in[3];
    const float* a1       = (const float*)d_in[4];
    const float* a2       = (const float*)d_in[5];
    float*       out      = (float*)d_out;

    const int n = in_sizes[0] / FF;     // 100000
    const int e = in_sizes[2];          // 1600000

    // ws layout
    __half*         xmv    = (__half*)d_ws;                         // n*256 fp16 = 51.2 MB
    unsigned short* Bth    = (unsigned short*)(xmv + (size_t)n * UU);
    unsigned short* Btl    = Bth + (size_t)FF * UU;
    int*            rowptr = (int*)(Btl + (size_t)FF * UU);         // n+1 ints
    float*          klpart = (float*)(rowptr + n + 2);

    const int nblocks = (n + BMG - 1) / BMG;          // 1563

    prep_b_kernel<<<16, 256, 0, stream>>>(kernelW, Bth, Btl);
    gemm_mfma_kernel<<<nblocks, 256, 0, stream>>>(features, Bth, Btl, xmv, klpart, n);
    rowptr_kernel<<<(n + 256) / 256, 256, 0, stream>>>(row, rowptr, n, e);
    spmm_kernel<<<(n + 3) / 4, 256, 0, stream>>>(rowptr, col, a1, a2, xmv, out, n);
    klreduce_kernel<<<1, 256, 0, stream>>>(klpart, nblocks, out + (size_t)n * UU);
}

// Round 7
// 383.584 us; speedup vs baseline: 1.8595x; 1.0220x over previous
//
#include <hip/hip_runtime.h>
#include <hip/hip_bf16.h>
#include <hip/hip_fp16.h>
#include <math.h>

#define FF 256      // feature dim (K)
#define UU 256      // units (N)
#define DD 128      // mean/var split
#define BMG 64      // gemm row tile
#define BKG 32      // gemm k tile
#define ALD 40      // LDS row stride in bf16 elems (32 + 8 pad -> 80B, 16B-aligned)

typedef short short8 __attribute__((ext_vector_type(8)));
typedef float f32x4  __attribute__((ext_vector_type(4)));

// round-to-nearest-even fp32 -> bf16 bits (finite inputs)
__device__ __forceinline__ unsigned short f2bf(float x) {
    unsigned int u = __float_as_uint(x);
    return (unsigned short)((u + 0x7fffu + ((u >> 16) & 1u)) >> 16);
}
__device__ __forceinline__ float bf2f(unsigned short b) {
    return __uint_as_float(((unsigned int)b) << 16);
}

// ---------------------------------------------------------------------------
// Kernel 0: split B into bf16 hi/lo, TRANSPOSED: Bt[n][k]
// ---------------------------------------------------------------------------
__global__ __launch_bounds__(256)
void prep_b_kernel(const float* __restrict__ B,
                   unsigned short* __restrict__ Bth,
                   unsigned short* __restrict__ Btl) {
    __shared__ float tile[64][65];
    const int t  = threadIdx.x;
    const int k0 = (blockIdx.x & 3) * 64;
    const int n0 = (blockIdx.x >> 2) * 64;
    #pragma unroll
    for (int i = 0; i < 16; ++i) {
        int idx = t + 256 * i;
        int kk = idx >> 6, nn = idx & 63;
        tile[kk][nn] = B[(size_t)(k0 + kk) * UU + n0 + nn];
    }
    __syncthreads();
    #pragma unroll
    for (int i = 0; i < 16; ++i) {
        int idx = t + 256 * i;
        int nn = idx >> 6, kk = idx & 63;
        float b = tile[kk][nn];
        unsigned short hb = f2bf(b);
        unsigned short lb = f2bf(b - bf2f(hb));
        Bth[(size_t)(n0 + nn) * FF + k0 + kk] = hb;
        Btl[(size_t)(n0 + nn) * FF + k0 + kk] = lb;
    }
}

// ---------------------------------------------------------------------------
// Kernel 1: bf16x3 MFMA GEMM + fused epilogue -> xmv fp16, kl partials.
// T14-lite: kt+1 global loads issued right after barrier, hidden under MFMA.
// ---------------------------------------------------------------------------
__global__ __launch_bounds__(256, 2)
void gemm_mfma_kernel(const float* __restrict__ A,
                      const unsigned short* __restrict__ Bth,
                      const unsigned short* __restrict__ Btl,
                      __half* __restrict__ xmv,
                      float* __restrict__ klpart,
                      int n) {
    __shared__ unsigned short Ah[BMG * ALD], Al[BMG * ALD];
    __shared__ unsigned short Bh[UU * ALD],  Bl[UU * ALD];
    __shared__ float kls[4];

    const int t    = threadIdx.x;
    const int lane = t & 63;
    const int w    = t >> 6;
    const int l15  = lane & 15;
    const int lk   = (lane >> 4) * 8;
    const int r0   = blockIdx.x * BMG;

    f32x4 acc[4][4];
    #pragma unroll
    for (int m = 0; m < 4; ++m)
        #pragma unroll
        for (int j = 0; j < 4; ++j)
            acc[m][j] = (f32x4){0.f, 0.f, 0.f, 0.f};

    // staging maps
    const int arow  = t >> 2;
    const int akseg = (t & 3) * 8;
    int garow = r0 + arow; if (garow >= n) garow = n - 1;
    const float* aptr = A + (size_t)garow * FF + akseg;

    // prefetch regs for current kt
    float4 pa0, pa1;
    short8 pbh[4], pbl[4];

    pa0 = *(const float4*)(aptr + 0);
    pa1 = *(const float4*)(aptr + 4);
    #pragma unroll
    for (int p = 0; p < 4; ++p) {
        int slot = t + 256 * p;
        int nr = slot >> 2, ks = (slot & 3) * 8;
        pbh[p] = *(const short8*)(Bth + (size_t)nr * FF + 0 + ks);
        pbl[p] = *(const short8*)(Btl + (size_t)nr * FF + 0 + ks);
    }

    for (int kt = 0; kt < FF; kt += BKG) {
        // ---- write staged regs -> LDS ----
        {
            float av[8] = {pa0.x, pa0.y, pa0.z, pa0.w, pa1.x, pa1.y, pa1.z, pa1.w};
            short8 hv, lv;
            #pragma unroll
            for (int i = 0; i < 8; ++i) {
                unsigned short hb = f2bf(av[i]);
                unsigned short lb = f2bf(av[i] - bf2f(hb));
                hv[i] = (short)hb; lv[i] = (short)lb;
            }
            *(short8*)(Ah + arow * ALD + akseg) = hv;
            *(short8*)(Al + arow * ALD + akseg) = lv;
            #pragma unroll
            for (int p = 0; p < 4; ++p) {
                int slot = t + 256 * p;
                int nr = slot >> 2, ks = (slot & 3) * 8;
                *(short8*)(Bh + nr * ALD + ks) = pbh[p];
                *(short8*)(Bl + nr * ALD + ks) = pbl[p];
            }
        }
        __syncthreads();

        // ---- issue kt+1 global loads (overlap with MFMA below) ----
        const int kt2 = kt + BKG;
        if (kt2 < FF) {
            pa0 = *(const float4*)(aptr + kt2);
            pa1 = *(const float4*)(aptr + kt2 + 4);
            #pragma unroll
            for (int p = 0; p < 4; ++p) {
                int slot = t + 256 * p;
                int nr = slot >> 2, ks = (slot & 3) * 8;
                pbh[p] = *(const short8*)(Bth + (size_t)nr * FF + kt2 + ks);
                pbl[p] = *(const short8*)(Btl + (size_t)nr * FF + kt2 + ks);
            }
        }

        // ---- fragments + MFMA ----
        short8 fah[4], fal[4], fbh[4], fbl[4];
        #pragma unroll
        for (int m = 0; m < 4; ++m) {
            int row = 16 * m + l15;
            fah[m] = *(const short8*)(Ah + row * ALD + lk);
            fal[m] = *(const short8*)(Al + row * ALD + lk);
        }
        #pragma unroll
        for (int j = 0; j < 4; ++j) {
            int nn = (j < 2) ? (32 * w + 16 * j + l15)
                             : (DD + 32 * w + 16 * (j - 2) + l15);
            fbh[j] = *(const short8*)(Bh + nn * ALD + lk);
            fbl[j] = *(const short8*)(Bl + nn * ALD + lk);
        }
        #pragma unroll
        for (int m = 0; m < 4; ++m)
            #pragma unroll
            for (int j = 0; j < 4; ++j) {
                acc[m][j] = __builtin_amdgcn_mfma_f32_16x16x32_bf16(fah[m], fbh[j], acc[m][j], 0, 0, 0);
                acc[m][j] = __builtin_amdgcn_mfma_f32_16x16x32_bf16(fal[m], fbh[j], acc[m][j], 0, 0, 0);
                acc[m][j] = __builtin_amdgcn_mfma_f32_16x16x32_bf16(fah[m], fbl[j], acc[m][j], 0, 0, 0);
            }
        __syncthreads();
    }

    // ---- fused epilogue: D row = (lane>>4)*4 + reg, col = l15 ----
    float klsum = 0.f;
    const int rbase = (lane >> 4) * 4;
    #pragma unroll
    for (int m = 0; m < 4; ++m)
        #pragma unroll
        for (int reg = 0; reg < 4; ++reg) {
            const int gr = r0 + 16 * m + rbase + reg;
            if (gr < n) {
                #pragma unroll
                for (int j = 0; j < 2; ++j) {
                    float h1 = acc[m][j][reg];
                    float h2 = acc[m][j + 2][reg];
                    float mm = h1 > 0.f ? h1 : expm1f(h1);
                    float vv = h2 > 0.f ? h2 : 0.f;
                    klsum += mm * mm + vv - logf(1e-8f + vv) - 1.f;
                    float att = expf(-vv);
                    const int cm = 32 * w + 16 * j + l15;
                    xmv[(size_t)gr * UU + cm]      = __float2half(mm * att);
                    xmv[(size_t)gr * UU + cm + DD] = __float2half(vv * att * att);
                }
            }
        }

    #pragma unroll
    for (int off = 32; off > 0; off >>= 1)
        klsum += __shfl_down(klsum, off, 64);
    if (lane == 0) kls[w] = klsum;
    __syncthreads();
    if (t == 0) klpart[blockIdx.x] = kls[0] + kls[1] + kls[2] + kls[3];
}

// ---------------------------------------------------------------------------
// Kernel 2a: rowptr[r] = lower_bound(row, r), r in [0, n]
// ---------------------------------------------------------------------------
__global__ __launch_bounds__(256)
void rowptr_kernel(const int* __restrict__ rowi, int* __restrict__ rowptr,
                   int n, int e) {
    const int r = blockIdx.x * 256 + threadIdx.x;
    if (r > n) return;
    int lo = 0, hi = e;
    while (lo < hi) { int mid = (lo + hi) >> 1; if (rowi[mid] < r) lo = mid + 1; else hi = mid; }
    rowptr[r] = lo;
}

// ---------------------------------------------------------------------------
// Kernel 2b: SpMM v3. TWO waves per row (edges split contiguously), edge
// metadata loaded once per wave as vector loads then shfl-broadcast per edge.
// Removes the uniform-load -> gather latency chain; doubles in-flight gathers.
// ---------------------------------------------------------------------------
__device__ __forceinline__ void fma4h(float4& a, float w, uint2 v) {
    __half2 p = *(__half2*)&v.x, q = *(__half2*)&v.y;
    float2 pf = __half22float2(p), qf = __half22float2(q);
    a.x = fmaf(w, pf.x, a.x); a.y = fmaf(w, pf.y, a.y);
    a.z = fmaf(w, qf.x, a.z); a.w = fmaf(w, qf.y, a.w);
}

__global__ __launch_bounds__(256)
void spmm_kernel(const int* __restrict__ rowptr,
                 const int* __restrict__ coli,
                 const float* __restrict__ w1,
                 const float* __restrict__ w2,
                 const __half* __restrict__ xmv,
                 float* __restrict__ out,
                 int n) {
    __shared__ float red[2][64][4];          // partial sums from half=1 waves

    const int lane = threadIdx.x & 63;
    const int wv   = threadIdx.x >> 6;       // 0..3
    const int rl   = wv >> 1;                // row slot in block (0/1)
    const int half = wv & 1;                 // which half of the edge list
    const int r    = blockIdx.x * 2 + rl;
    const bool valid = r < n;
    const int rr   = valid ? r : (n - 1);

    const int lb  = rowptr[rr];
    const int ub  = rowptr[rr + 1];
    const int deg = ub - lb;
    const int hl  = (deg + 1) >> 1;
    const int start = lb + (half ? hl : 0);
    const int cnt   = half ? (deg - hl) : hl;

    const uint2* __restrict__ x2 = (const uint2*)xmv;   // 4 halfs / lane
    float4 a0 = make_float4(0.f,0.f,0.f,0.f), a1 = a0, a2 = a0, a3 = a0;

    for (int base = start; base < start + cnt; base += 64) {
        const int m = min(64, start + cnt - base);
        // one vector load per metadata stream, lane i <-> edge base+i
        const int   ce = (lane < m) ? coli[base + lane] : 0;
        const float wa = (lane < m) ? w1[base + lane]   : 0.f;
        const float wb = (lane < m) ? w2[base + lane]   : 0.f;

        int i = 0;
        for (; i + 4 <= m; i += 4) {
            const int c0 = __shfl(ce, i),     c1 = __shfl(ce, i + 1);
            const int c2 = __shfl(ce, i + 2), c3 = __shfl(ce, i + 3);
            const float wa0 = __shfl(wa, i),     wb0 = __shfl(wb, i);
            const float wa1 = __shfl(wa, i + 1), wb1 = __shfl(wb, i + 1);
            const float wa2 = __shfl(wa, i + 2), wb2 = __shfl(wb, i + 2);
            const float wa3 = __shfl(wa, i + 3), wb3 = __shfl(wb, i + 3);
            const float w0 = (lane < 32) ? wa0 : wb0;
            const float w1v = (lane < 32) ? wa1 : wb1;
            const float w2v = (lane < 32) ? wa2 : wb2;
            const float w3v = (lane < 32) ? wa3 : wb3;
            const uint2 v0 = x2[(size_t)c0 * 64 + lane];
            const uint2 v1 = x2[(size_t)c1 * 64 + lane];
            const uint2 v2 = x2[(size_t)c2 * 64 + lane];
            const uint2 v3 = x2[(size_t)c3 * 64 + lane];
            fma4h(a0, w0, v0);  fma4h(a1, w1v, v1);
            fma4h(a2, w2v, v2); fma4h(a3, w3v, v3);
        }
        for (; i < m; ++i) {
            const int c = __shfl(ce, i);
            const float waw = __shfl(wa, i), wbw = __shfl(wb, i);
            const float w = (lane < 32) ? waw : wbw;
            fma4h(a0, w, x2[(size_t)c * 64 + lane]);
        }
    }

    float4 s;
    s.x = (a0.x + a1.x) + (a2.x + a3.x);
    s.y = (a0.y + a1.y) + (a2.y + a3.y);
    s.z = (a0.z + a1.z) + (a2.z + a3.z);
    s.w = (a0.w + a1.w) + (a2.w + a3.w);

    if (half == 1) {
        red[rl][lane][0] = s.x; red[rl][lane][1] = s.y;
        red[rl][lane][2] = s.z; red[rl][lane][3] = s.w;
    }
    __syncthreads();
    if (half == 0 && valid) {
        f32x4 res;
        res[0] = s.x + red[rl][lane][0];
        res[1] = s.y + red[rl][lane][1];
        res[2] = s.z + red[rl][lane][2];
        res[3] = s.w + red[rl][lane][3];
        __builtin_nontemporal_store(res, (f32x4*)out + (size_t)r * 64 + lane);
    }
}

// ---------------------------------------------------------------------------
// Kernel 3: reduce kl partials
// ---------------------------------------------------------------------------
__global__ __launch_bounds__(256)
void klreduce_kernel(const float* __restrict__ klpart, int nparts,
                     float* __restrict__ dst) {
    __shared__ float tmp[4];
    const int t = threadIdx.x;
    float s = 0.f;
    for (int i = t; i < nparts; i += 256) s += klpart[i];
    #pragma unroll
    for (int off = 32; off > 0; off >>= 1)
        s += __shfl_down(s, off, 64);
    if ((t & 63) == 0) tmp[t >> 6] = s;
    __syncthreads();
    if (t == 0) dst[0] = (0.5f / (float)DD) * (tmp[0] + tmp[1] + tmp[2] + tmp[3]);
}

// ---------------------------------------------------------------------------
extern "C" void kernel_launch(void* const* d_in, const int* in_sizes, int n_in,
                              void* d_out, int out_size, void* d_ws, size_t ws_size,
                              hipStream_t stream) {
    const float* features = (const float*)d_in[0];
    const float* kernelW  = (const float*)d_in[1];
    const int*   row      = (const int*)d_in[2];
    const int*   col      = (const int*)d_in[3];
    const float* a1       = (const float*)d_in[4];
    const float* a2       = (const float*)d_in[5];
    float*       out      = (float*)d_out;

    const int n = in_sizes[0] / FF;     // 100000
    const int e = in_sizes[2];          // 1600000

    // ws layout
    __half*         xmv    = (__half*)d_ws;                         // n*256 fp16
    unsigned short* Bth    = (unsigned short*)(xmv + (size_t)n * UU);
    unsigned short* Btl    = Bth + (size_t)FF * UU;
    int*            rowptr = (int*)(Btl + (size_t)FF * UU);         // n+1 ints
    float*          klpart = (float*)(rowptr + n + 2);

    const int nblocks = (n + BMG - 1) / BMG;          // 1563

    prep_b_kernel<<<16, 256, 0, stream>>>(kernelW, Bth, Btl);
    gemm_mfma_kernel<<<nblocks, 256, 0, stream>>>(features, Bth, Btl, xmv, klpart, n);
    rowptr_kernel<<<(n + 256) / 256, 256, 0, stream>>>(row, rowptr, n, e);
    spmm_kernel<<<(n + 1) / 2, 256, 0, stream>>>(rowptr, col, a1, a2, xmv, out, n);
    klreduce_kernel<<<1, 256, 0, stream>>>(klpart, nblocks, out + (size_t)n * UU);
}